// Round 12
// baseline (328.815 us; speedup 1.0000x reference)
//
#include <hip/hip_runtime.h>
#include <hip/hip_cooperative_groups.h>
#include <cmath>

namespace cg = cooperative_groups;

#define H_DIM 75
#define W_DIM 100
#define HW 7500
#define KSEL 2000
#define BATCH 8
#define CIN 512
#define FDIM 128

typedef short v4s __attribute__((ext_vector_type(4)));
typedef short v8s __attribute__((ext_vector_type(8)));
typedef float v16f __attribute__((ext_vector_type(16)));

__device__ __forceinline__ unsigned int map_key(float f) {
  unsigned int u = __float_as_uint(f);
  return (u & 0x80000000u) ? ~u : (u | 0x80000000u);
}

__device__ __forceinline__ float fast_tanh(float x) {
  float e = __expf(2.0f * x);
  return 1.0f - 2.0f * __builtin_amdgcn_rcpf(e + 1.0f);
}

__device__ __forceinline__ unsigned short bf16_rne(float v) {
  unsigned int u = __float_as_uint(v);
  unsigned int r = u + 0x7FFFu + ((u >> 16) & 1u);
  return (unsigned short)(r >> 16);
}
__device__ __forceinline__ float bf16_to_f(unsigned short h) {
  return __uint_as_float(((unsigned int)h) << 16);
}

// MEGA (cooperative, 256 blocks x 1024 thr = 1 block/CU, co-resident):
//   Stage A: blocks 0..7 topk (radix select + packed scan + off-sort +
//            neighbor lists, verified r3 path); blocks 8..15 weight split.
//   Stage B: gemm1 = r3 champion code, bitwise-identical, tid<256
//            (idle waves execute the matching 33 anonymous barriers).
//   Stage C: gemm2_fused champion code, tid<256 (1 matching barrier).
//   Stage D: out, grid-strided over all 1024 threads.
// grid.sync() between stages is the SANCTIONED cross-XCD visibility
// mechanism (r10's manual flags + plain loads faulted on stale poisoned
// L2 lines; kernel-boundary/coop-sync semantics are the fix).
// WHY: r1/r4/r11 arithmetic shows non-gemm1 cost is a stable ~176us vs
// ~95us of estimated kernel work -> ~80us of launch overhead / hidden
// kernel cost. One dispatch deletes all gaps AND makes the true compute
// time visible in top-5 (poison fills cut off everything <70us).
// gemm1 ledger (r3..r11, seven structures, 65-98us): r3 shape optimal.
__global__ __launch_bounds__(1024, 4) void mega(
    const float* __restrict__ feat, const float* __restrict__ pred,
    const float* __restrict__ w1, const float* __restrict__ b1,
    const float* __restrict__ w2, const float* __restrict__ b2,
    int* __restrict__ off2_ws, int* __restrict__ perm_ws,
    float* __restrict__ out_idx,
    unsigned short* __restrict__ nbr, unsigned char* __restrict__ cnt,
    unsigned short* __restrict__ w1t_hi, unsigned short* __restrict__ w1t_lo,
    unsigned short* __restrict__ w2t_hi, unsigned short* __restrict__ w2t_lo,
    float* __restrict__ G, float* __restrict__ x1, float* __restrict__ Hm,
    float* __restrict__ out0)
{
  cg::grid_group grid = cg::this_grid();
  __shared__ __align__(16) unsigned char smem[48672];  // union of all stages
  const int tid = threadIdx.x;
  const int bid = blockIdx.x;

  // ======================= Stage A: topk + weights =======================
  if (bid < BATCH) {
    unsigned int* keys     = (unsigned int*)smem;              // 30000 B
    unsigned int* whist    = (unsigned int*)(smem + 30000);    // 16384 B
    unsigned int* hist     = (unsigned int*)(smem + 46384);    //  1024 B
    unsigned int* partials = (unsigned int*)(smem + 47408);    //    64 B
    unsigned int* sP       = (unsigned int*)(smem + 47472);    // prefix,kth

    const int b = bid;
    const int lane = tid & 63, w = tid >> 6;
    const float* scores = pred + (size_t)b * 3 * HW;  // channel 0
    for (int i = tid; i < HW; i += 1024) keys[i] = map_key(scores[i]);
    if (tid == 0) { sP[0] = 0u; sP[1] = KSEL; }
    __syncthreads();

    // radix select, MSB-first, 8 bits/round
    for (int shift = 24; shift >= 0; shift -= 8) {
      for (int i = tid; i < 16 * 256; i += 1024) whist[i] = 0u;
      __syncthreads();
      unsigned int pref = sP[0];
      unsigned int maskhi = (shift == 24) ? 0u : (0xFFFFFFFFu << (shift + 8));
      for (int i = tid; i < HW; i += 1024) {
        unsigned int k = keys[i];
        if ((k & maskhi) == pref)
          atomicAdd(&whist[w * 256 + ((k >> shift) & 0xFFu)], 1u);
      }
      __syncthreads();
      if (tid < 256) {
        unsigned int s = 0;
        #pragma unroll
        for (int ww = 0; ww < 16; ++ww) s += whist[ww * 256 + tid];
        hist[tid] = s;
      }
      __syncthreads();
      if (tid < 64) {
        unsigned int b0 = hist[tid * 4], b1 = hist[tid * 4 + 1];
        unsigned int b2v = hist[tid * 4 + 2], b3 = hist[tid * 4 + 3];
        unsigned int kth = sP[1];
        unsigned int T = b0 + b1 + b2v + b3;
        #pragma unroll
        for (int off = 1; off < 64; off <<= 1) {
          unsigned int t = __shfl_down(T, off, 64);
          if (tid + off < 64) T += t;       // inclusive suffix of lane totals
        }
        unsigned int U = __shfl_down(T, 1, 64);
        if (tid == 63) U = 0u;              // suffix strictly after this lane
        unsigned int s3 = b3 + U, s2 = b2v + s3, s1 = b1 + s2, s0 = b0 + s1;
        if (s0 >= kth && s1 < kth) { sP[0] = pref | ((unsigned)(4 * tid + 0) << shift); sP[1] = kth - s1; }
        if (s1 >= kth && s2 < kth) { sP[0] = pref | ((unsigned)(4 * tid + 1) << shift); sP[1] = kth - s2; }
        if (s2 >= kth && s3 < kth) { sP[0] = pref | ((unsigned)(4 * tid + 2) << shift); sP[1] = kth - s3; }
        if (s3 >= kth && U  < kth) { sP[0] = pref | ((unsigned)(4 * tid + 3) << shift); sP[1] = kth - U; }
      }
      __syncthreads();
    }
    const unsigned int thresh = sP[0];

    // selection flags: gt in low 16 bits, eq in high 16, packed
    unsigned int local[8];
    unsigned int sum = 0;
    #pragma unroll
    for (int e = 0; e < 8; ++e) {
      int i = tid * 8 + e;
      unsigned int p = 0;
      if (i < HW) {
        unsigned int ky = keys[i];
        if (ky > thresh) p = 1u;
        else if (ky == thresh) p = (1u << 16);
      }
      local[e] = p; sum += p;
    }
    __syncthreads();   // keys dead — overlay
    short* pos_of  = (short*)keys;
    int*   s_idx_sh = (int*)((char*)keys + 15000);
    for (int i = tid; i < HW; i += 1024) pos_of[i] = -1;

    // two-level exclusive prefix scan
    unsigned int inc = sum;
    #pragma unroll
    for (int off = 1; off < 64; off <<= 1) {
      unsigned int t = __shfl_up(inc, off, 64);
      if (lane >= off) inc += t;
    }
    if (lane == 63) partials[w] = inc;
    __syncthreads();
    if (tid < 16) {
      unsigned int v = partials[tid];
      #pragma unroll
      for (int off = 1; off < 16; off <<= 1) {
        unsigned int t = __shfl_up(v, off, 64);
        if (tid >= off) v += t;
      }
      partials[tid] = v;
    }
    __syncthreads();
    unsigned int total = partials[15];
    unsigned int run = (w ? partials[w - 1] : 0u) + inc - sum;
    unsigned int ties = (unsigned int)KSEL - (total & 0xFFFFu);
    #pragma unroll
    for (int e = 0; e < 8; ++e) {
      int i = tid * 8 + e;
      unsigned int p = local[e];
      unsigned int gt_pref = run & 0xFFFFu;
      unsigned int eq_pref = run >> 16;
      bool sel = (p & 1u) || (((p >> 16) != 0u) && eq_pref < ties);
      if (sel) {
        unsigned int pos = gt_pref + (eq_pref < ties ? eq_pref : ties);
        out_idx[b * KSEL + pos] = (float)i;
        s_idx_sh[pos] = i;
        pos_of[i] = (short)pos;
      }
      run += p;
    }
    __syncthreads();

    // counting sort by y' = i % 75 -> off-sorted processing order
    if (tid < 128) hist[tid] = 0u;
    __syncthreads();
    for (int pos = tid; pos < KSEL; pos += 1024)
      atomicAdd(&hist[s_idx_sh[pos] % H_DIM], 1u);
    __syncthreads();
    if (tid == 0) {
      unsigned int run2 = 0u;
      for (int j = 0; j < H_DIM; ++j) { unsigned int t = hist[j]; hist[j] = run2; run2 += t; }
    }
    __syncthreads();
    for (int pos = tid; pos < KSEL; pos += 1024) {
      int i = s_idx_sh[pos];
      int y = i % H_DIM;
      unsigned int j = atomicAdd(&hist[y], 1u);
      off2_ws[b * KSEL + j] = (i % H_DIM) * W_DIM + i / H_DIM;  // gather quirk
      perm_ws[b * KSEL + j] = pos;
    }

    // neighbor lists; rows padded to 9 (pad=0)
    for (int i = tid; i < KSEL; i += 1024) {
      int q = s_idx_sh[i];
      int py = q / W_DIM, px = q % W_DIM;
      unsigned short tmp[9];
      int c = 0;
      #pragma unroll
      for (int dy = -1; dy <= 1; ++dy) {
        int y = py + dy;
        if ((unsigned)y >= (unsigned)H_DIM) continue;
        #pragma unroll
        for (int dx = -1; dx <= 1; ++dx) {
          int x = px + dx;
          if ((unsigned)x >= (unsigned)W_DIM) continue;
          short p = pos_of[y * W_DIM + x];
          if (p >= 0) tmp[c++] = (unsigned short)p;
        }
      }
      #pragma unroll
      for (int t = 0; t < 9; ++t)
        nbr[(size_t)(b * KSEL + i) * 9 + t] = (t < c) ? tmp[t] : (unsigned short)0;
      cnt[b * KSEL + i] = (unsigned char)c;
    }
  } else if (bid < BATCH + 8) {            // weight split: 8 blocks
    int base = (bid - BATCH) * 1024 + tid;
    for (int e = base; e < CIN * FDIM + FDIM * FDIM; e += 8 * 1024) {
      if (e < CIN * FDIM) {
        int k = e & (CIN - 1), f = e >> 9;   // k-inner: coalesced writes
        float v = w1[k * FDIM + f];
        unsigned short hi = bf16_rne(v);
        unsigned short lo = bf16_rne(v - bf16_to_f(hi));
        w1t_hi[(size_t)f * CIN + k] = hi;
        w1t_lo[(size_t)f * CIN + k] = lo;
      } else {
        int e2 = e - CIN * FDIM;
        int k = e2 & (FDIM - 1), f = e2 >> 7;
        float v = w2[k * FDIM + f];
        unsigned short hi = bf16_rne(v);
        unsigned short lo = bf16_rne(v - bf16_to_f(hi));
        w2t_hi[(size_t)f * FDIM + k] = hi;
        w2t_lo[(size_t)f * FDIM + k] = lo;
      }
    }
  }
  grid.sync();

  // ======================= Stage B: gemm1 (r3 champion) ==================
  {
    const int b = bid >> 5;
    const int n0 = (bid & 31) * 64;
    if (tid < 256) {
      unsigned short (*a_hi)[64][20] = (unsigned short (*)[64][20])smem;
      unsigned short (*a_lo)[64][20] = (unsigned short (*)[64][20])(smem + 5120);
      const int lane = tid & 63, w = tid >> 6;
      const int wr = w & 1, wc = w >> 1;
      const int q = lane >> 5, m = lane & 31;
      v16f acc0, acc1;
      #pragma unroll
      for (int i = 0; i < 16; ++i) { acc0[i] = 0.f; acc1[i] = 0.f; }
      const int an = wr * 32 + m;
      const int f0 = wc * 64 + m;
      const int n_st = tid & 63, ks = (tid >> 6) * 4;
      int nidx = n0 + n_st;
      if (nidx > KSEL - 1) nidx = KSEL - 1;  // clamp: dup rows never stored
      const float* fb = feat + (size_t)b * CIN * HW + off2_ws[b * KSEL + nidx];

      #pragma unroll
      for (int j = 0; j < 4; ++j) {          // prologue: stage chunk 0
        float v = fb[(size_t)(ks + j) * HW];
        v = fminf(fmaxf(v, 0.f), 6.f);
        unsigned short hi = bf16_rne(v);
        a_hi[0][n_st][ks + j] = hi;
        a_lo[0][n_st][ks + j] = bf16_rne(v - bf16_to_f(hi));
      }
      __syncthreads();                       // barrier 1

      for (int kk = 0; kk < CIN; kk += 16) { // 32 iters, 1 barrier each
        const int p = (kk >> 4) & 1;
        if (kk + 16 < CIN) {
          #pragma unroll
          for (int j = 0; j < 4; ++j) {
            float v = fb[(size_t)(kk + 16 + ks + j) * HW];
            v = fminf(fmaxf(v, 0.f), 6.f);
            unsigned short hi = bf16_rne(v);
            a_hi[p ^ 1][n_st][ks + j] = hi;
            a_lo[p ^ 1][n_st][ks + j] = bf16_rne(v - bf16_to_f(hi));
          }
        }
        v4s ah0 = *(const v4s*)&a_hi[p][an][q * 8];
        v4s ah1 = *(const v4s*)&a_hi[p][an][q * 8 + 4];
        v4s al0 = *(const v4s*)&a_lo[p][an][q * 8];
        v4s al1 = *(const v4s*)&a_lo[p][an][q * 8 + 4];
        v8s avh = __builtin_shufflevector(ah0, ah1, 0, 1, 2, 3, 4, 5, 6, 7);
        v8s avl = __builtin_shufflevector(al0, al1, 0, 1, 2, 3, 4, 5, 6, 7);
        v8s b0h = *(const v8s*)&w1t_hi[(size_t)f0 * CIN + kk + q * 8];
        v8s b0l = *(const v8s*)&w1t_lo[(size_t)f0 * CIN + kk + q * 8];
        v8s b1h = *(const v8s*)&w1t_hi[(size_t)(f0 + 32) * CIN + kk + q * 8];
        v8s b1l = *(const v8s*)&w1t_lo[(size_t)(f0 + 32) * CIN + kk + q * 8];
        acc0 = __builtin_amdgcn_mfma_f32_32x32x16_bf16(avh, b0h, acc0, 0, 0, 0);
        acc0 = __builtin_amdgcn_mfma_f32_32x32x16_bf16(avh, b0l, acc0, 0, 0, 0);
        acc0 = __builtin_amdgcn_mfma_f32_32x32x16_bf16(avl, b0h, acc0, 0, 0, 0);
        acc1 = __builtin_amdgcn_mfma_f32_32x32x16_bf16(avh, b1h, acc1, 0, 0, 0);
        acc1 = __builtin_amdgcn_mfma_f32_32x32x16_bf16(avh, b1l, acc1, 0, 0, 0);
        acc1 = __builtin_amdgcn_mfma_f32_32x32x16_bf16(avl, b1h, acc1, 0, 0, 0);
        __syncthreads();
      }
      float* ob = G + (size_t)b * KSEL * FDIM;
      const int* pb = perm_ws + b * KSEL;
      #pragma unroll
      for (int reg = 0; reg < 16; ++reg) {
        int row = n0 + wr * 32 + (reg & 3) + 8 * (reg >> 2) + 4 * q;
        if (row < KSEL) {
          int pr = pb[row];                  // scatter to sorted-pos G row
          ob[(size_t)pr * FDIM + f0]      = acc0[reg];
          ob[(size_t)pr * FDIM + f0 + 32] = acc1[reg];
        }
      }
    } else {
      for (int i = 0; i < 33; ++i) __syncthreads();  // match barrier count
    }
  }
  grid.sync();

  // ======================= Stage C: gemm2 (champion) =====================
  {
    const int b = bid >> 5;
    const int n0 = (bid & 31) * 64;
    if (tid < 256) {
      unsigned short (*xh)[FDIM] = (unsigned short (*)[FDIM])smem;
      unsigned short (*xl)[FDIM] = (unsigned short (*)[FDIM])(smem + 16384);
      const int g = tid >> 5, lane32 = tid & 31;
      const float4* G4 = (const float4*)G + (size_t)b * KSEL * 32;

      #pragma unroll 2
      for (int rr = 0; rr < 8; ++rr) {
        const int r = rr * 8 + g;
        const int node = n0 + r;
        const int nodec = (node > KSEL - 1) ? KSEL - 1 : node;
        const size_t bi = (size_t)b * KSEL + nodec;
        const unsigned short* nb = nbr + bi * 9;
        unsigned short idx[9];
        #pragma unroll
        for (int t = 0; t < 9; ++t) idx[t] = nb[t];
        const int c = cnt[bi];
        float4 v[9];
        #pragma unroll
        for (int t = 0; t < 9; ++t) v[t] = G4[(size_t)idx[t] * 32 + lane32];
        float4 acc = ((const float4*)b1)[nodec * 32 + lane32];
        #pragma unroll
        for (int t = 0; t < 9; ++t) {
          float mk = (t < c) ? 1.f : 0.f;
          acc.x = fmaf(v[t].x, mk, acc.x);
          acc.y = fmaf(v[t].y, mk, acc.y);
          acc.z = fmaf(v[t].z, mk, acc.z);
          acc.w = fmaf(v[t].w, mk, acc.w);
        }
        if (node < KSEL) ((float4*)x1)[bi * 32 + lane32] = acc;
        ushort4 h, l;
        h.x = bf16_rne(acc.x); l.x = bf16_rne(acc.x - bf16_to_f(h.x));
        h.y = bf16_rne(acc.y); l.y = bf16_rne(acc.y - bf16_to_f(h.y));
        h.z = bf16_rne(acc.z); l.z = bf16_rne(acc.z - bf16_to_f(h.z));
        h.w = bf16_rne(acc.w); l.w = bf16_rne(acc.w - bf16_to_f(h.w));
        const int cs = (lane32 * 4) ^ ((r & 15) << 3);  // swizzled col
        *(ushort4*)&xh[r][cs] = h;
        *(ushort4*)&xl[r][cs] = l;
      }
      __syncthreads();                       // barrier 1

      const int lane = tid & 63, w = tid >> 6;
      const int wr = w & 1, wc = w >> 1;
      const int q = lane >> 5, m = lane & 31;
      const int ar = wr * 32 + m;
      const int f0 = wc * 64 + m;
      v16f acc0, acc1;
      #pragma unroll
      for (int i = 0; i < 16; ++i) { acc0[i] = 0.f; acc1[i] = 0.f; }
      #pragma unroll
      for (int k0 = 0; k0 < FDIM; k0 += 16) {
        const int ac = (k0 + q * 8) ^ ((ar & 15) << 3);
        v8s avh = *(const v8s*)&xh[ar][ac];
        v8s avl = *(const v8s*)&xl[ar][ac];
        v8s b0h = *(const v8s*)&w2t_hi[(size_t)f0 * FDIM + k0 + q * 8];
        v8s b0l = *(const v8s*)&w2t_lo[(size_t)f0 * FDIM + k0 + q * 8];
        v8s b1h = *(const v8s*)&w2t_hi[(size_t)(f0 + 32) * FDIM + k0 + q * 8];
        v8s b1l = *(const v8s*)&w2t_lo[(size_t)(f0 + 32) * FDIM + k0 + q * 8];
        acc0 = __builtin_amdgcn_mfma_f32_32x32x16_bf16(avh, b0h, acc0, 0, 0, 0);
        acc0 = __builtin_amdgcn_mfma_f32_32x32x16_bf16(avh, b0l, acc0, 0, 0, 0);
        acc0 = __builtin_amdgcn_mfma_f32_32x32x16_bf16(avl, b0h, acc0, 0, 0, 0);
        acc1 = __builtin_amdgcn_mfma_f32_32x32x16_bf16(avh, b1h, acc1, 0, 0, 0);
        acc1 = __builtin_amdgcn_mfma_f32_32x32x16_bf16(avh, b1l, acc1, 0, 0, 0);
        acc1 = __builtin_amdgcn_mfma_f32_32x32x16_bf16(avl, b1h, acc1, 0, 0, 0);
      }
      float* ob = Hm + (size_t)b * KSEL * FDIM;
      #pragma unroll
      for (int reg = 0; reg < 16; ++reg) {
        int row = n0 + wr * 32 + (reg & 3) + 8 * (reg >> 2) + 4 * q;
        if (row < KSEL) {
          ob[(size_t)row * FDIM + f0]      = acc0[reg];
          ob[(size_t)row * FDIM + f0 + 32] = acc1[reg];
        }
      }
    } else {
      __syncthreads();                       // match barrier count
    }
  }
  grid.sync();

  // ======================= Stage D: out (grid-strided) ===================
  {
    const int g = tid >> 5, lane = tid & 31;
    for (int idx = bid * 32 + g; idx < BATCH * KSEL; idx += 256 * 32) {
      const int bb = idx / KSEL;
      const int node = idx - bb * KSEL;
      const size_t bi = (size_t)bb * KSEL + node;
      const unsigned short* nb = nbr + bi * 9;
      unsigned short idxv[9];
      #pragma unroll
      for (int t = 0; t < 9; ++t) idxv[t] = nb[t];
      const int c = cnt[bi];
      const float4* H4 = (const float4*)Hm + (size_t)bb * KSEL * 32;
      float4 v[9];
      #pragma unroll
      for (int t = 0; t < 9; ++t) v[t] = H4[(size_t)idxv[t] * 32 + lane];
      float4 acc = ((const float4*)b2)[node * 32 + lane];
      float4 xv = ((const float4*)x1)[bi * 32 + lane];
      acc.x += xv.x; acc.y += xv.y; acc.z += xv.z; acc.w += xv.w;
      #pragma unroll
      for (int t = 0; t < 9; ++t) {
        float mk = (t < c) ? 1.f : 0.f;
        acc.x = fmaf(v[t].x, mk, acc.x);
        acc.y = fmaf(v[t].y, mk, acc.y);
        acc.z = fmaf(v[t].z, mk, acc.z);
        acc.w = fmaf(v[t].w, mk, acc.w);
      }
      float4 r;
      r.x = fast_tanh(acc.x); r.y = fast_tanh(acc.y);
      r.z = fast_tanh(acc.z); r.w = fast_tanh(acc.w);
      ((float4*)out0)[bi * 32 + lane] = r;
    }
  }
}

extern "C" void kernel_launch(void* const* d_in, const int* in_sizes, int n_in,
                              void* d_out, int out_size, void* d_ws, size_t ws_size,
                              hipStream_t stream) {
  const float* feat = (const float*)d_in[0];
  const float* pred = (const float*)d_in[1];
  const float* w1   = (const float*)d_in[2];
  const float* b1   = (const float*)d_in[3];
  const float* w2   = (const float*)d_in[4];
  const float* b2   = (const float*)d_in[5];
  float* out0 = (float*)d_out;                              // (8,2000,128) fp32
  float* out_idx = out0 + (size_t)BATCH * KSEL * FDIM;      // (8,2000) as fp32

  // workspace layout (256B-aligned), ~25.3 MB
  char* ws = (char*)d_ws;
  int*            off2_ws = (int*)(ws + 0);                  //     64,000 B
  int*            perm_ws = (int*)(ws + 64256);              //     64,000 B
  unsigned short* nbr     = (unsigned short*)(ws + 128512);  //    288,000 B
  unsigned char*  cnt     = (unsigned char*)(ws + 416512);   //     16,000 B
  float*          G       = (float*)(ws + 432640);           //  8,192,000 B
  float*          x1      = (float*)(ws + 8624640);          //  8,192,000 B
  float*          Hm      = (float*)(ws + 16816640);         //  8,192,000 B
  unsigned short* w1t_hi  = (unsigned short*)(ws + 25008640); //   131,072 B
  unsigned short* w1t_lo  = (unsigned short*)(ws + 25139712); //   131,072 B
  unsigned short* w2t_hi  = (unsigned short*)(ws + 25270784); //    32,768 B
  unsigned short* w2t_lo  = (unsigned short*)(ws + 25303552); //    32,768 B

  void* args[] = {
    (void*)&feat, (void*)&pred, (void*)&w1, (void*)&b1, (void*)&w2, (void*)&b2,
    (void*)&off2_ws, (void*)&perm_ws, (void*)&out_idx, (void*)&nbr, (void*)&cnt,
    (void*)&w1t_hi, (void*)&w1t_lo, (void*)&w2t_hi, (void*)&w2t_lo,
    (void*)&G, (void*)&x1, (void*)&Hm, (void*)&out0
  };
  hipLaunchCooperativeKernel((void*)mega, dim3(256), dim3(1024), args, 0, stream);
}

// Round 13
// 232.010 us; speedup vs baseline: 1.4172x; 1.4172x over previous
//
#include <hip/hip_runtime.h>
#include <cmath>

#define H_DIM 75
#define W_DIM 100
#define HW 7500
#define KSEL 2000
#define BATCH 8
#define CIN 512
#define FDIM 128

typedef short v4s __attribute__((ext_vector_type(4)));
typedef short v8s __attribute__((ext_vector_type(8)));
typedef float v16f __attribute__((ext_vector_type(16)));

__device__ __forceinline__ unsigned int map_key(float f) {
  unsigned int u = __float_as_uint(f);
  return (u & 0x80000000u) ? ~u : (u | 0x80000000u);
}

__device__ __forceinline__ float fast_tanh(float x) {
  float e = __expf(2.0f * x);
  return 1.0f - 2.0f * __builtin_amdgcn_rcpf(e + 1.0f);
}

__device__ __forceinline__ unsigned short bf16_rne(float v) {
  unsigned int u = __float_as_uint(v);
  unsigned int r = u + 0x7FFFu + ((u >> 16) & 1u);
  return (unsigned short)(r >> 16);
}
__device__ __forceinline__ float bf16_to_f(unsigned short h) {
  return __uint_as_float(((unsigned int)h) << 16);
}

// K1 (fused): blocks 0..7 per-batch top-K (radix select, per-wave privatized
// histograms) + packed scan (exact lax.top_k+sort semantics) + OFF-SORTED
// permutation (counting sort on y'=i%75; r1->r3: 333MB->~100MB, -48us) +
// neighbor lists. Blocks 8..15: w1/w2 bf16 hi/lo transposed split.
// Session ledger: gemm1 floor ~65us across 7 structures (r3..r11); r10
// intra-kernel producer-consumer faulted (cross-XCD stale reads); r12 coop
// mega measured whole-pipeline compute ~176us but coop launch adds ~100us+
// overhead -> 4-launch structure retained; r13 widens the back-end gathers.
__global__ __launch_bounds__(1024) void topk_nbr_kernel(
    const float* __restrict__ pred, const float* __restrict__ w1,
    const float* __restrict__ w2,
    int* __restrict__ off2_ws, int* __restrict__ perm_ws,
    float* __restrict__ out_idx,
    unsigned short* __restrict__ nbr, unsigned char* __restrict__ cnt,
    unsigned short* __restrict__ w1t_hi, unsigned short* __restrict__ w1t_lo,
    unsigned short* __restrict__ w2t_hi, unsigned short* __restrict__ w2t_lo)
{
  __shared__ unsigned int keys[HW];        // 30 KB; reused: pos_of + s_idx
  __shared__ unsigned int whist[16 * 256]; // per-wave histograms, 16 KB
  __shared__ unsigned int hist[256];
  __shared__ unsigned int partials[16];
  __shared__ unsigned int s_prefix, s_kth;
  const int tid = threadIdx.x;

  if (blockIdx.x >= BATCH) {               // weight split: 8 blocks x 1024 thr
    int base = (blockIdx.x - BATCH) * 1024 + tid;
    for (int e = base; e < CIN * FDIM + FDIM * FDIM; e += 8 * 1024) {
      if (e < CIN * FDIM) {
        int k = e & (CIN - 1), f = e >> 9;   // k-inner: coalesced writes
        float v = w1[k * FDIM + f];
        unsigned short hi = bf16_rne(v);
        unsigned short lo = bf16_rne(v - bf16_to_f(hi));
        w1t_hi[(size_t)f * CIN + k] = hi;
        w1t_lo[(size_t)f * CIN + k] = lo;
      } else {
        int e2 = e - CIN * FDIM;
        int k = e2 & (FDIM - 1), f = e2 >> 7;
        float v = w2[k * FDIM + f];
        unsigned short hi = bf16_rne(v);
        unsigned short lo = bf16_rne(v - bf16_to_f(hi));
        w2t_hi[(size_t)f * FDIM + k] = hi;
        w2t_lo[(size_t)f * FDIM + k] = lo;
      }
    }
    return;
  }

  const int b = blockIdx.x;
  const int lane = tid & 63, w = tid >> 6;
  const float* scores = pred + (size_t)b * 3 * HW;  // channel 0 of predict
  for (int i = tid; i < HW; i += 1024) keys[i] = map_key(scores[i]);
  if (tid == 0) { s_prefix = 0u; s_kth = KSEL; }
  __syncthreads();

  // radix select, MSB-first, 8 bits/round
  for (int shift = 24; shift >= 0; shift -= 8) {
    for (int i = tid; i < 16 * 256; i += 1024) whist[i] = 0u;
    __syncthreads();
    unsigned int pref = s_prefix;
    unsigned int maskhi = (shift == 24) ? 0u : (0xFFFFFFFFu << (shift + 8));
    for (int i = tid; i < HW; i += 1024) {
      unsigned int k = keys[i];
      if ((k & maskhi) == pref)
        atomicAdd(&whist[w * 256 + ((k >> shift) & 0xFFu)], 1u);
    }
    __syncthreads();
    if (tid < 256) {
      unsigned int s = 0;
      #pragma unroll
      for (int ww = 0; ww < 16; ++ww) s += whist[ww * 256 + tid];
      hist[tid] = s;
    }
    __syncthreads();
    if (tid < 64) {
      unsigned int b0 = hist[tid * 4], b1 = hist[tid * 4 + 1];
      unsigned int b2 = hist[tid * 4 + 2], b3 = hist[tid * 4 + 3];
      unsigned int kth = s_kth;
      unsigned int T = b0 + b1 + b2 + b3;
      #pragma unroll
      for (int off = 1; off < 64; off <<= 1) {
        unsigned int t = __shfl_down(T, off, 64);
        if (tid + off < 64) T += t;         // inclusive suffix of lane totals
      }
      unsigned int U = __shfl_down(T, 1, 64);
      if (tid == 63) U = 0u;                // suffix strictly after this lane
      unsigned int s3 = b3 + U, s2 = b2 + s3, s1 = b1 + s2, s0 = b0 + s1;
      if (s0 >= kth && s1 < kth) { s_prefix = pref | ((unsigned)(4 * tid + 0) << shift); s_kth = kth - s1; }
      if (s1 >= kth && s2 < kth) { s_prefix = pref | ((unsigned)(4 * tid + 1) << shift); s_kth = kth - s2; }
      if (s2 >= kth && s3 < kth) { s_prefix = pref | ((unsigned)(4 * tid + 2) << shift); s_kth = kth - s3; }
      if (s3 >= kth && U  < kth) { s_prefix = pref | ((unsigned)(4 * tid + 3) << shift); s_kth = kth - U; }
    }
    __syncthreads();
  }
  const unsigned int thresh = s_prefix;

  // selection flags: gt in low 16 bits, eq in high 16, packed
  unsigned int local[8];
  unsigned int sum = 0;
  #pragma unroll
  for (int e = 0; e < 8; ++e) {
    int i = tid * 8 + e;
    unsigned int p = 0;
    if (i < HW) {
      unsigned int ky = keys[i];
      if (ky > thresh) p = 1u;
      else if (ky == thresh) p = (1u << 16);
    }
    local[e] = p; sum += p;
  }
  __syncthreads();   // keys dead — overlay
  short* pos_of  = (short*)keys;
  int*   s_idx_sh = (int*)((char*)keys + 15000);
  for (int i = tid; i < HW; i += 1024) pos_of[i] = -1;

  // two-level exclusive prefix scan
  unsigned int inc = sum;
  #pragma unroll
  for (int off = 1; off < 64; off <<= 1) {
    unsigned int t = __shfl_up(inc, off, 64);
    if (lane >= off) inc += t;
  }
  if (lane == 63) partials[w] = inc;
  __syncthreads();
  if (tid < 16) {
    unsigned int v = partials[tid];
    #pragma unroll
    for (int off = 1; off < 16; off <<= 1) {
      unsigned int t = __shfl_up(v, off, 64);
      if (tid >= off) v += t;
    }
    partials[tid] = v;
  }
  __syncthreads();
  unsigned int total = partials[15];
  unsigned int run = (w ? partials[w - 1] : 0u) + inc - sum;
  unsigned int ties = (unsigned int)KSEL - (total & 0xFFFFu);
  #pragma unroll
  for (int e = 0; e < 8; ++e) {
    int i = tid * 8 + e;
    unsigned int p = local[e];
    unsigned int gt_pref = run & 0xFFFFu;
    unsigned int eq_pref = run >> 16;
    bool sel = (p & 1u) || (((p >> 16) != 0u) && eq_pref < ties);
    if (sel) {
      unsigned int pos = gt_pref + (eq_pref < ties ? eq_pref : ties);
      out_idx[b * KSEL + pos] = (float)i;
      s_idx_sh[pos] = i;
      pos_of[i] = (short)pos;
    }
    run += p;
  }
  __syncthreads();

  // ---- counting sort by y' = i % 75 -> off-sorted processing order ----
  if (tid < 128) hist[tid] = 0u;
  __syncthreads();
  for (int pos = tid; pos < KSEL; pos += 1024)
    atomicAdd(&hist[s_idx_sh[pos] % H_DIM], 1u);
  __syncthreads();
  if (tid == 0) {
    unsigned int run2 = 0u;
    for (int j = 0; j < H_DIM; ++j) { unsigned int t = hist[j]; hist[j] = run2; run2 += t; }
  }
  __syncthreads();
  for (int pos = tid; pos < KSEL; pos += 1024) {
    int i = s_idx_sh[pos];
    int y = i % H_DIM;
    unsigned int j = atomicAdd(&hist[y], 1u);
    off2_ws[b * KSEL + j] = (i % H_DIM) * W_DIM + i / H_DIM;  // gather quirk
    perm_ws[b * KSEL + j] = pos;
  }

  // neighbor lists; rows padded to 9 (pad=0) so consumers load unconditionally
  for (int i = tid; i < KSEL; i += 1024) {
    int q = s_idx_sh[i];
    int py = q / W_DIM, px = q % W_DIM;
    unsigned short tmp[9];
    int c = 0;
    #pragma unroll
    for (int dy = -1; dy <= 1; ++dy) {
      int y = py + dy;
      if ((unsigned)y >= (unsigned)H_DIM) continue;
      #pragma unroll
      for (int dx = -1; dx <= 1; ++dx) {
        int x = px + dx;
        if ((unsigned)x >= (unsigned)W_DIM) continue;
        short p = pos_of[y * W_DIM + x];
        if (p >= 0) tmp[c++] = (unsigned short)p;
      }
    }
    #pragma unroll
    for (int t = 0; t < 9; ++t)
      nbr[(size_t)(b * KSEL + i) * 9 + t] = (t < c) ? tmp[t] : (unsigned short)0;
    cnt[b * KSEL + i] = (unsigned char)c;
  }
}

// K2 (fused gather+gemm1, r3 champion, UNCHANGED): G = clip(gather(feat))@w1.
__global__ __launch_bounds__(256) void gemm1_fused(
    const float* __restrict__ feat, const int* __restrict__ off2_ws,
    const int* __restrict__ perm_ws,
    const unsigned short* __restrict__ w1t_hi,
    const unsigned short* __restrict__ w1t_lo,
    float* __restrict__ G)
{
  __shared__ unsigned short a_hi[2][64][20], a_lo[2][64][20];  // 10 KB
  const int b = blockIdx.y;
  const int n0 = blockIdx.x * 64;
  const int tid = threadIdx.x;
  const int lane = tid & 63, w = tid >> 6;
  const int wr = w & 1, wc = w >> 1;
  const int q = lane >> 5, m = lane & 31;
  v16f acc0, acc1;
  #pragma unroll
  for (int i = 0; i < 16; ++i) { acc0[i] = 0.f; acc1[i] = 0.f; }
  const int an = wr * 32 + m;
  const int f0 = wc * 64 + m;
  const int n_st = tid & 63, ks = (tid >> 6) * 4;
  int nidx = n0 + n_st;
  if (nidx > KSEL - 1) nidx = KSEL - 1;   // clamp: dup rows never stored
  const float* fb = feat + (size_t)b * CIN * HW + off2_ws[b * KSEL + nidx];

  #pragma unroll
  for (int j = 0; j < 4; ++j) {               // prologue: stage chunk 0
    float v = fb[(size_t)(ks + j) * HW];
    v = fminf(fmaxf(v, 0.f), 6.f);
    unsigned short hi = bf16_rne(v);
    a_hi[0][n_st][ks + j] = hi;
    a_lo[0][n_st][ks + j] = bf16_rne(v - bf16_to_f(hi));
  }
  __syncthreads();

  for (int kk = 0; kk < CIN; kk += 16) {
    const int p = (kk >> 4) & 1;
    if (kk + 16 < CIN) {                      // stage next into other buffer
      #pragma unroll
      for (int j = 0; j < 4; ++j) {
        float v = fb[(size_t)(kk + 16 + ks + j) * HW];
        v = fminf(fmaxf(v, 0.f), 6.f);
        unsigned short hi = bf16_rne(v);
        a_hi[p ^ 1][n_st][ks + j] = hi;
        a_lo[p ^ 1][n_st][ks + j] = bf16_rne(v - bf16_to_f(hi));
      }
    }
    v4s ah0 = *(const v4s*)&a_hi[p][an][q * 8];
    v4s ah1 = *(const v4s*)&a_hi[p][an][q * 8 + 4];
    v4s al0 = *(const v4s*)&a_lo[p][an][q * 8];
    v4s al1 = *(const v4s*)&a_lo[p][an][q * 8 + 4];
    v8s avh = __builtin_shufflevector(ah0, ah1, 0, 1, 2, 3, 4, 5, 6, 7);
    v8s avl = __builtin_shufflevector(al0, al1, 0, 1, 2, 3, 4, 5, 6, 7);
    v8s b0h = *(const v8s*)&w1t_hi[(size_t)f0 * CIN + kk + q * 8];
    v8s b0l = *(const v8s*)&w1t_lo[(size_t)f0 * CIN + kk + q * 8];
    v8s b1h = *(const v8s*)&w1t_hi[(size_t)(f0 + 32) * CIN + kk + q * 8];
    v8s b1l = *(const v8s*)&w1t_lo[(size_t)(f0 + 32) * CIN + kk + q * 8];
    acc0 = __builtin_amdgcn_mfma_f32_32x32x16_bf16(avh, b0h, acc0, 0, 0, 0);
    acc0 = __builtin_amdgcn_mfma_f32_32x32x16_bf16(avh, b0l, acc0, 0, 0, 0);
    acc0 = __builtin_amdgcn_mfma_f32_32x32x16_bf16(avl, b0h, acc0, 0, 0, 0);
    acc1 = __builtin_amdgcn_mfma_f32_32x32x16_bf16(avh, b1h, acc1, 0, 0, 0);
    acc1 = __builtin_amdgcn_mfma_f32_32x32x16_bf16(avh, b1l, acc1, 0, 0, 0);
    acc1 = __builtin_amdgcn_mfma_f32_32x32x16_bf16(avl, b1h, acc1, 0, 0, 0);
    __syncthreads();
  }
  float* ob = G + (size_t)b * KSEL * FDIM;
  const int* pb = perm_ws + b * KSEL;
  #pragma unroll
  for (int reg = 0; reg < 16; ++reg) {
    int row = n0 + wr * 32 + (reg & 3) + 8 * (reg >> 2) + 4 * q;
    if (row < KSEL) {
      int pr = pb[row];                      // scatter to sorted-pos G row
      ob[(size_t)pr * FDIM + f0]      = acc0[reg];
      ob[(size_t)pr * FDIM + f0 + 32] = acc1[reg];
    }
  }
}

// K3 (fused x1+gemm2, WIDENED to 512 threads): phase 1's 9-neighbor G
// gather now runs 16 row-groups in flight (4 rows/thread instead of 8) —
// 2x memory-level parallelism for the latency-bound gather. Phase 2 (MFMA)
// unchanged, executed by tid<256; all 512 threads cross the one barrier.
// Per-node FMA order unchanged -> x1/Hm bitwise identical.
__global__ __launch_bounds__(512) void gemm2_fused(
    const float* __restrict__ G, const float* __restrict__ b1,
    const unsigned short* __restrict__ nbr, const unsigned char* __restrict__ cnt,
    const unsigned short* __restrict__ w2t_hi,
    const unsigned short* __restrict__ w2t_lo,
    float* __restrict__ x1, float* __restrict__ Hm)
{
  __shared__ __align__(16) unsigned short xh[64][FDIM];  // 16 KB
  __shared__ __align__(16) unsigned short xl[64][FDIM];  // 16 KB
  const int b = blockIdx.y;
  const int n0 = blockIdx.x * 64;
  const int tid = threadIdx.x;
  const int g = tid >> 5, lane32 = tid & 31;             // 16 row-groups
  const float4* G4 = (const float4*)G + (size_t)b * KSEL * 32;

  #pragma unroll
  for (int rr = 0; rr < 4; ++rr) {         // 4 rows/thread (was 8)
    const int r = rr * 16 + g;
    const int node = n0 + r;
    const int nodec = (node > KSEL - 1) ? KSEL - 1 : node;
    const size_t bi = (size_t)b * KSEL + nodec;
    const unsigned short* nb = nbr + bi * 9;
    unsigned short idx[9];
    #pragma unroll
    for (int t = 0; t < 9; ++t) idx[t] = nb[t];
    const int c = cnt[bi];
    float4 v[9];
    #pragma unroll
    for (int t = 0; t < 9; ++t) v[t] = G4[(size_t)idx[t] * 32 + lane32];
    float4 acc = ((const float4*)b1)[nodec * 32 + lane32];
    #pragma unroll
    for (int t = 0; t < 9; ++t) {
      float mk = (t < c) ? 1.f : 0.f;
      acc.x = fmaf(v[t].x, mk, acc.x);
      acc.y = fmaf(v[t].y, mk, acc.y);
      acc.z = fmaf(v[t].z, mk, acc.z);
      acc.w = fmaf(v[t].w, mk, acc.w);
    }
    if (node < KSEL) ((float4*)x1)[bi * 32 + lane32] = acc;
    ushort4 h, l;
    h.x = bf16_rne(acc.x); l.x = bf16_rne(acc.x - bf16_to_f(h.x));
    h.y = bf16_rne(acc.y); l.y = bf16_rne(acc.y - bf16_to_f(h.y));
    h.z = bf16_rne(acc.z); l.z = bf16_rne(acc.z - bf16_to_f(h.z));
    h.w = bf16_rne(acc.w); l.w = bf16_rne(acc.w - bf16_to_f(h.w));
    const int cs = (lane32 * 4) ^ ((r & 15) << 3);   // swizzled col (shorts)
    *(ushort4*)&xh[r][cs] = h;
    *(ushort4*)&xl[r][cs] = l;
  }
  __syncthreads();

  if (tid < 256) {                         // MFMA phase: 4 waves as champion
    const int lane = tid & 63, w = tid >> 6;
    const int wr = w & 1, wc = w >> 1;
    const int q = lane >> 5, m = lane & 31;
    const int ar = wr * 32 + m;            // local A row in LDS
    const int f0 = wc * 64 + m;
    v16f acc0, acc1;
    #pragma unroll
    for (int i = 0; i < 16; ++i) { acc0[i] = 0.f; acc1[i] = 0.f; }
    #pragma unroll
    for (int k0 = 0; k0 < FDIM; k0 += 16) {
      const int ac = (k0 + q * 8) ^ ((ar & 15) << 3);
      v8s avh = *(const v8s*)&xh[ar][ac];
      v8s avl = *(const v8s*)&xl[ar][ac];
      v8s b0h = *(const v8s*)&w2t_hi[(size_t)f0 * FDIM + k0 + q * 8];
      v8s b0l = *(const v8s*)&w2t_lo[(size_t)f0 * FDIM + k0 + q * 8];
      v8s b1h = *(const v8s*)&w2t_hi[(size_t)(f0 + 32) * FDIM + k0 + q * 8];
      v8s b1l = *(const v8s*)&w2t_lo[(size_t)(f0 + 32) * FDIM + k0 + q * 8];
      acc0 = __builtin_amdgcn_mfma_f32_32x32x16_bf16(avh, b0h, acc0, 0, 0, 0);
      acc0 = __builtin_amdgcn_mfma_f32_32x32x16_bf16(avh, b0l, acc0, 0, 0, 0);
      acc0 = __builtin_amdgcn_mfma_f32_32x32x16_bf16(avl, b0h, acc0, 0, 0, 0);
      acc1 = __builtin_amdgcn_mfma_f32_32x32x16_bf16(avh, b1h, acc1, 0, 0, 0);
      acc1 = __builtin_amdgcn_mfma_f32_32x32x16_bf16(avh, b1l, acc1, 0, 0, 0);
      acc1 = __builtin_amdgcn_mfma_f32_32x32x16_bf16(avl, b1h, acc1, 0, 0, 0);
    }
    float* ob = Hm + (size_t)b * KSEL * FDIM;
    #pragma unroll
    for (int reg = 0; reg < 16; ++reg) {
      int row = n0 + wr * 32 + (reg & 3) + 8 * (reg >> 2) + 4 * q;
      if (row < KSEL) {
        ob[(size_t)row * FDIM + f0]      = acc0[reg];
        ob[(size_t)row * FDIM + f0 + 32] = acc1[reg];
      }
    }
  }
}

// K4: out[i] = tanh(b2[i] + x1[i] + sum_{j in nbr(i)} H[j]) — widened to
// 512 threads / 16 nodes per block (fewer blocks, same per-node math).
__global__ __launch_bounds__(512) void out_kernel(
    const float* __restrict__ Hm, const float* __restrict__ x1,
    const float* __restrict__ b2,
    const unsigned short* __restrict__ nbr, const unsigned char* __restrict__ cnt,
    float* __restrict__ out)
{
  const int g = threadIdx.x >> 5, lane = threadIdx.x & 31;
  const int node = blockIdx.x * 16 + g;
  const int bb = blockIdx.y;
  const size_t bi = (size_t)bb * KSEL + node;
  const unsigned short* nb = nbr + bi * 9;
  unsigned short idx[9];
  #pragma unroll
  for (int t = 0; t < 9; ++t) idx[t] = nb[t];
  const int c = cnt[bi];
  const float4* H4 = (const float4*)Hm + (size_t)bb * KSEL * 32;
  float4 v[9];
  #pragma unroll
  for (int t = 0; t < 9; ++t) v[t] = H4[(size_t)idx[t] * 32 + lane];
  float4 acc = ((const float4*)b2)[node * 32 + lane];
  float4 xv = ((const float4*)x1)[bi * 32 + lane];
  acc.x += xv.x; acc.y += xv.y; acc.z += xv.z; acc.w += xv.w;
  #pragma unroll
  for (int t = 0; t < 9; ++t) {
    float mk = (t < c) ? 1.f : 0.f;
    acc.x = fmaf(v[t].x, mk, acc.x);
    acc.y = fmaf(v[t].y, mk, acc.y);
    acc.z = fmaf(v[t].z, mk, acc.z);
    acc.w = fmaf(v[t].w, mk, acc.w);
  }
  float4 r;
  r.x = fast_tanh(acc.x); r.y = fast_tanh(acc.y);
  r.z = fast_tanh(acc.z); r.w = fast_tanh(acc.w);
  ((float4*)out)[bi * 32 + lane] = r;
}

extern "C" void kernel_launch(void* const* d_in, const int* in_sizes, int n_in,
                              void* d_out, int out_size, void* d_ws, size_t ws_size,
                              hipStream_t stream) {
  const float* feat = (const float*)d_in[0];
  const float* pred = (const float*)d_in[1];
  const float* w1   = (const float*)d_in[2];
  const float* b1   = (const float*)d_in[3];
  const float* w2   = (const float*)d_in[4];
  const float* b2   = (const float*)d_in[5];
  float* out0 = (float*)d_out;                              // (8,2000,128) fp32
  float* out_idx = out0 + (size_t)BATCH * KSEL * FDIM;      // (8,2000) as fp32

  // workspace layout (256B-aligned), ~25.3 MB
  char* ws = (char*)d_ws;
  int*            off2_ws = (int*)(ws + 0);                  //     64,000 B
  int*            perm_ws = (int*)(ws + 64256);              //     64,000 B
  unsigned short* nbr     = (unsigned short*)(ws + 128512);  //    288,000 B
  unsigned char*  cnt     = (unsigned char*)(ws + 416512);   //     16,000 B
  float*          G       = (float*)(ws + 432640);           //  8,192,000 B
  float*          x1      = (float*)(ws + 8624640);          //  8,192,000 B
  float*          Hm      = (float*)(ws + 16816640);         //  8,192,000 B
  unsigned short* w1t_hi  = (unsigned short*)(ws + 25008640); //   131,072 B
  unsigned short* w1t_lo  = (unsigned short*)(ws + 25139712); //   131,072 B
  unsigned short* w2t_hi  = (unsigned short*)(ws + 25270784); //    32,768 B
  unsigned short* w2t_lo  = (unsigned short*)(ws + 25303552); //    32,768 B

  topk_nbr_kernel<<<BATCH + 8, 1024, 0, stream>>>(
      pred, w1, w2, off2_ws, perm_ws, out_idx, nbr, cnt,
      w1t_hi, w1t_lo, w2t_hi, w2t_lo);
  gemm1_fused<<<dim3(32, BATCH), 256, 0, stream>>>(
      feat, off2_ws, perm_ws, w1t_hi, w1t_lo, G);
  gemm2_fused<<<dim3(32, BATCH), 512, 0, stream>>>(G, b1, nbr, cnt, w2t_hi, w2t_lo, x1, Hm);
  out_kernel<<<dim3(KSEL / 16, BATCH), 512, 0, stream>>>(Hm, x1, b2, nbr, cnt, out0);
}